// Round 1
// baseline (355.103 us; speedup 1.0000x reference)
//
#include <hip/hip_runtime.h>
#include <hip/hip_bf16.h>
#include <stdint.h>

// ---------------------------------------------------------------------------
// DFT_12223476924859: STFT via two GEMMs sharing the frame operand.
//   Out0[b,k,t] = sum_n wcos[k,n] * xpad[b, t*512+n]
//   Out1[b,k,t] = sum_n (-wsin[k,n]) * xpad[b, t*512+n]
// M=2048 (k), K=2048 (n), N=8208 columns (c = b*513+t).
// Round 1: bf16 MFMA 128x128 tile, BK=64, global_load_lds(16B), XOR-swizzled
// LDS (2-way bank aliasing = free). grid.z=2 selects cos / -sin matrix.
// ---------------------------------------------------------------------------

#define N_FFT   2048
#define HOP     512
#define BATCH   16
#define LENGTH  262144
#define PADLEN  (LENGTH + N_FFT)          // 264192
#define FRAMES  513
#define NCOL    (BATCH * FRAMES)          // 8208
#define OHALF   ((size_t)BATCH * N_FFT * FRAMES)  // 16,809,984
#define WELEMS  (N_FFT * N_FFT)           // 4,194,304
#define XELEMS  (BATCH * PADLEN)          // 4,227,072

typedef __bf16 bf16;
typedef __bf16 bf16x8 __attribute__((ext_vector_type(8)));
typedef float  f32x4  __attribute__((ext_vector_type(4)));

// ---------------------------- prep kernels ---------------------------------

__global__ void prep_x(const float* __restrict__ x, bf16* __restrict__ xp) {
    int i = blockIdx.x * 256 + threadIdx.x;
    if (i >= XELEMS) return;
    int b = i / PADLEN;
    int p = i - b * PADLEN;
    int j = p - (N_FFT / 2);
    j = (j < 0) ? -j : j;
    j = (j >= LENGTH) ? (2 * LENGTH - 2 - j) : j;
    xp[i] = (bf16)x[(size_t)b * LENGTH + j];
}

__global__ void prep_w(const float* __restrict__ wcos, const float* __restrict__ wsin,
                       bf16* __restrict__ wc, bf16* __restrict__ wsn) {
    int i = blockIdx.x * 256 + threadIdx.x;   // one float4 per thread
    int base = i * 4;
    if (base < WELEMS) {
        float4 v = *(const float4*)(wcos + base);
        wc[base + 0] = (bf16)v.x;  wc[base + 1] = (bf16)v.y;
        wc[base + 2] = (bf16)v.z;  wc[base + 3] = (bf16)v.w;
    } else {
        int b2 = base - WELEMS;
        if (b2 >= WELEMS) return;
        float4 v = *(const float4*)(wsin + b2);
        wsn[b2 + 0] = (bf16)(-v.x);  wsn[b2 + 1] = (bf16)(-v.y);
        wsn[b2 + 2] = (bf16)(-v.z);  wsn[b2 + 3] = (bf16)(-v.w);
    }
}

// ----------------------------- GEMM kernel ---------------------------------
// block = 256 threads = 4 waves. Tile 128(M) x 128(N), BK=64.
// Wave (mhalf,nhalf) owns a 64x64 quadrant = 4x4 tiles of 16x16.
// LDS layout (A and B identical): row-major [row][BK], 16B chunk at slot s
// holds global k-chunk j = s ^ (row&7)  (XOR swizzle, keeps staging
// lane-contiguous for global_load_lds while ds_read_b128 is 2-way aliased).

__global__ __launch_bounds__(256) void dft_gemm(
    const bf16* __restrict__ xp,   // [BATCH][PADLEN] bf16
    const bf16* __restrict__ wc,   // [2048][2048] bf16 cos
    const bf16* __restrict__ wsn,  // [2048][2048] bf16 -sin
    float* __restrict__ out)
{
    __shared__ __align__(16) bf16 Asm[128 * 64];
    __shared__ __align__(16) bf16 Bsm[128 * 64];

    const int tid   = threadIdx.x;
    const int lane  = tid & 63;
    const int wave  = tid >> 6;
    const int quad  = lane >> 4;
    const int l15   = lane & 15;
    const int mhalf = wave >> 1;
    const int nhalf = wave & 1;

    const int bx = blockIdx.x;   // n-tile: columns [bx*128, bx*128+128)
    const int by = blockIdx.y;   // m-tile: freq rows [by*128, by*128+128)
    const int bz = blockIdx.z;   // 0 = cos -> out0, 1 = -sin -> out1

    const bf16* Ap    = bz ? wsn : wc;
    float*      obase = out + (size_t)bz * OHALF;

    // --- loop-invariant staging offsets (element units) ---
    int gA[4], gB[4];
    #pragma unroll
    for (int i = 0; i < 4; ++i) {
        int s = i * 256 + tid;        // chunk id, 0..1023
        int r = s >> 3;               // tile row 0..127
        int j = (s & 7) ^ (r & 7);    // global k-chunk this slot holds
        gA[i] = (by * 128 + r) * 2048 + j * 8;
        int c = bx * 128 + r;
        if (c > NCOL - 1) c = NCOL - 1;          // clamp pad columns
        int b = c / FRAMES;
        int t = c - b * FRAMES;
        gB[i] = b * PADLEN + t * HOP + j * 8;
    }

    // --- loop-invariant ds_read offsets (element units) ---
    int offA[2][4], offB[2][4];
    #pragma unroll
    for (int mt = 0; mt < 4; ++mt) {
        int row = mhalf * 64 + mt * 16 + l15;
        #pragma unroll
        for (int ks = 0; ks < 2; ++ks) {
            int j = ks * 4 + quad;
            offA[ks][mt] = row * 64 + ((j ^ (row & 7)) * 8);
        }
    }
    #pragma unroll
    for (int nt = 0; nt < 4; ++nt) {
        int rown = nhalf * 64 + nt * 16 + l15;
        #pragma unroll
        for (int ks = 0; ks < 2; ++ks) {
            int j = ks * 4 + quad;
            offB[ks][nt] = rown * 64 + ((j ^ (rown & 7)) * 8);
        }
    }

    f32x4 acc[4][4];
    const f32x4 zero = {0.f, 0.f, 0.f, 0.f};
    #pragma unroll
    for (int mt = 0; mt < 4; ++mt)
        #pragma unroll
        for (int nt = 0; nt < 4; ++nt) acc[mt][nt] = zero;

    const int ldsbase0 = wave * 64 * 8;   // wave-uniform; HW adds lane*16B

    for (int k0 = 0; k0 < 2048; k0 += 64) {
        __syncthreads();   // previous compute done before LDS overwrite
        #pragma unroll
        for (int i = 0; i < 4; ++i) {
            int lb = ldsbase0 + i * 256 * 8;
            __builtin_amdgcn_global_load_lds(
                (const __attribute__((address_space(1))) uint32_t*)(Ap + gA[i] + k0),
                (__attribute__((address_space(3))) uint32_t*)(Asm + lb),
                16, 0, 0);
            __builtin_amdgcn_global_load_lds(
                (const __attribute__((address_space(1))) uint32_t*)(xp + gB[i] + k0),
                (__attribute__((address_space(3))) uint32_t*)(Bsm + lb),
                16, 0, 0);
        }
        __syncthreads();   // compiler drains vmcnt(0) before barrier
        #pragma unroll
        for (int ks = 0; ks < 2; ++ks) {
            bf16x8 af[4], bf[4];
            #pragma unroll
            for (int mt = 0; mt < 4; ++mt)
                af[mt] = *(const bf16x8*)(Asm + offA[ks][mt]);
            #pragma unroll
            for (int nt = 0; nt < 4; ++nt)
                bf[nt] = *(const bf16x8*)(Bsm + offB[ks][nt]);
            #pragma unroll
            for (int mt = 0; mt < 4; ++mt)
                #pragma unroll
                for (int nt = 0; nt < 4; ++nt)
                    acc[mt][nt] = __builtin_amdgcn_mfma_f32_16x16x32_bf16(
                        af[mt], bf[nt], acc[mt][nt], 0, 0, 0);
        }
    }

    // --- epilogue: D col = lane&15 (our column c), row = quad*4+reg (freq) ---
    #pragma unroll
    for (int nt = 0; nt < 4; ++nt) {
        int c = bx * 128 + nhalf * 64 + nt * 16 + l15;
        if (c >= NCOL) continue;
        int b = c / FRAMES;
        int t = c - b * FRAMES;
        float* op = obase + (size_t)b * (N_FFT * FRAMES) + t;
        int rowbase = by * 128 + mhalf * 64 + quad * 4;
        #pragma unroll
        for (int mt = 0; mt < 4; ++mt) {
            int row = rowbase + mt * 16;
            #pragma unroll
            for (int r = 0; r < 4; ++r)
                op[(size_t)(row + r) * FRAMES] = acc[mt][nt][r];
        }
    }
}

// ------------------------- fallback (ws too small) -------------------------

__global__ void dft_naive(const float* __restrict__ x,
                          const float* __restrict__ wsin,
                          const float* __restrict__ wcos,
                          float* __restrict__ out)
{
    size_t i = (size_t)blockIdx.x * 256 + threadIdx.x;
    if (i >= OHALF) return;
    int t = (int)(i % FRAMES);
    size_t r = i / FRAMES;
    int k = (int)(r % N_FFT);
    int b = (int)(r / N_FFT);
    float sr = 0.f, si = 0.f;
    int base = t * HOP - N_FFT / 2;
    for (int n = 0; n < N_FFT; ++n) {
        int j = base + n;
        j = (j < 0) ? -j : ((j >= LENGTH) ? (2 * LENGTH - 2 - j) : j);
        float xv = x[(size_t)b * LENGTH + j];
        sr += xv * wcos[(size_t)k * N_FFT + n];
        si += xv * wsin[(size_t)k * N_FFT + n];
    }
    out[i] = sr;
    out[OHALF + i] = -si;
}

// ------------------------------- launch ------------------------------------

extern "C" void kernel_launch(void* const* d_in, const int* in_sizes, int n_in,
                              void* d_out, int out_size, void* d_ws, size_t ws_size,
                              hipStream_t stream) {
    const float* x    = (const float*)d_in[0];
    const float* wsin = (const float*)d_in[1];
    const float* wcos = (const float*)d_in[2];
    float* out = (float*)d_out;

    const size_t need = (size_t)(XELEMS + 2 * WELEMS) * sizeof(bf16); // ~25.2 MB
    if (ws_size < need) {
        dft_naive<<<(int)((OHALF + 255) / 256), 256, 0, stream>>>(x, wsin, wcos, out);
        return;
    }

    bf16* xp  = (bf16*)d_ws;
    bf16* wc  = xp + XELEMS;
    bf16* wsn = wc + WELEMS;

    prep_x<<<(XELEMS + 255) / 256, 256, 0, stream>>>(x, xp);
    prep_w<<<(2 * WELEMS / 4 + 255) / 256, 256, 0, stream>>>(wcos, wsin, wc, wsn);

    dim3 grid(65, 16, 2);   // 65 n-tiles x 16 m-tiles x {cos, -sin}
    dft_gemm<<<grid, 256, 0, stream>>>(xp, wc, wsn, out);
}

// Round 2
// 341.136 us; speedup vs baseline: 1.0409x; 1.0409x over previous
//
#include <hip/hip_runtime.h>
#include <hip/hip_bf16.h>
#include <stdint.h>

// ---------------------------------------------------------------------------
// DFT_12223476924859: STFT via GEMM + spectral symmetry.
//   out0[b,k,t] = sum_n wcos[k,n] * xpad[b, t*512+n]
//   out1[b,k,t] = sum_n (-wsin[k,n]) * xpad[b, t*512+n]
// Symmetry: wcos[2048-k,:]==wcos[k,:], wsin[2048-k,:]==-wsin[k,:]
//   => out0[2048-k] = out0[k];  out1[2048-k] = -out1[k]   (k=1..1023)
// GEMM computes only k=0..1023 (M=1024, half the FLOPs) and writes the
// mirror rows from registers in the epilogue. Row k=1024 (Nyquist) is a
// per-column dot-product kernel. 128x128 tiles, BK=64, global_load_lds(16B),
// XOR-swizzled LDS.
// ---------------------------------------------------------------------------

#define N_FFT   2048
#define HOP     512
#define BATCH   16
#define LENGTH  262144
#define PADLEN  (LENGTH + N_FFT)          // 264192
#define FRAMES  513
#define NCOL    (BATCH * FRAMES)          // 8208
#define OHALF   ((size_t)BATCH * N_FFT * FRAMES)  // 16,809,984
#define WELEMS  (N_FFT * N_FFT)           // 4,194,304
#define XELEMS  (BATCH * PADLEN)          // 4,227,072

typedef __bf16 bf16;
typedef __bf16 bf16x8 __attribute__((ext_vector_type(8)));
typedef float  f32x4  __attribute__((ext_vector_type(4)));

// ---------------------------- prep kernels ---------------------------------

// 8 outputs per thread, one 16B store.
__global__ void prep_x(const float* __restrict__ x, bf16* __restrict__ xp) {
    int i8 = (blockIdx.x * 256 + threadIdx.x) * 8;
    if (i8 >= XELEMS) return;
    int b = i8 / PADLEN;                 // 8 | PADLEN, so all 8 in one batch
    int p0 = i8 - b * PADLEN;
    const float* xb = x + (size_t)b * LENGTH;
    bf16x8 v;
    #pragma unroll
    for (int e = 0; e < 8; ++e) {
        int j = p0 + e - (N_FFT / 2);
        j = (j < 0) ? -j : j;
        j = (j >= LENGTH) ? (2 * LENGTH - 2 - j) : j;
        v[e] = (bf16)xb[j];
    }
    *(bf16x8*)(xp + i8) = v;
}

// 8 elements per thread: two float4 loads -> one 16B bf16x8 store.
__global__ void prep_w(const float* __restrict__ wcos, const float* __restrict__ wsin,
                       bf16* __restrict__ wc, bf16* __restrict__ wsn) {
    int i = blockIdx.x * 256 + threadIdx.x;
    int base = i * 8;
    if (base < WELEMS) {
        float4 a = *(const float4*)(wcos + base);
        float4 c = *(const float4*)(wcos + base + 4);
        bf16x8 v = { (bf16)a.x, (bf16)a.y, (bf16)a.z, (bf16)a.w,
                     (bf16)c.x, (bf16)c.y, (bf16)c.z, (bf16)c.w };
        *(bf16x8*)(wc + base) = v;
    } else {
        int b2 = base - WELEMS;
        if (b2 >= WELEMS) return;
        float4 a = *(const float4*)(wsin + b2);
        float4 c = *(const float4*)(wsin + b2 + 4);
        bf16x8 v = { (bf16)(-a.x), (bf16)(-a.y), (bf16)(-a.z), (bf16)(-a.w),
                     (bf16)(-c.x), (bf16)(-c.y), (bf16)(-c.z), (bf16)(-c.w) };
        *(bf16x8*)(wsn + b2) = v;
    }
}

// ----------------------------- GEMM kernel ---------------------------------
// block = 256 threads = 4 waves. Tile 128(M) x 128(N), BK=64, M range 0..1023.
// Epilogue writes row k and mirror row 2048-k (sign-flipped for bz=1).

__global__ __launch_bounds__(256) void dft_gemm(
    const bf16* __restrict__ xp,   // [BATCH][PADLEN] bf16
    const bf16* __restrict__ wc,   // [2048][2048] bf16 cos
    const bf16* __restrict__ wsn,  // [2048][2048] bf16 -sin
    float* __restrict__ out)
{
    __shared__ __align__(16) bf16 Asm[128 * 64];
    __shared__ __align__(16) bf16 Bsm[128 * 64];

    const int tid   = threadIdx.x;
    const int lane  = tid & 63;
    const int wave  = tid >> 6;
    const int quad  = lane >> 4;
    const int l15   = lane & 15;
    const int mhalf = wave >> 1;
    const int nhalf = wave & 1;

    const int bx = blockIdx.x;   // n-tile: columns [bx*128, bx*128+128)
    const int by = blockIdx.y;   // m-tile: freq rows [by*128, ...), by in 0..7
    const int bz = blockIdx.z;   // 0 = cos -> out0, 1 = -sin -> out1

    const bf16* Ap    = bz ? wsn : wc;
    float*      obase = out + (size_t)bz * OHALF;
    const float sg    = bz ? -1.f : 1.f;   // mirror-row sign

    // --- loop-invariant staging offsets (element units) ---
    int gA[4], gB[4];
    #pragma unroll
    for (int i = 0; i < 4; ++i) {
        int s = i * 256 + tid;        // chunk id, 0..1023
        int r = s >> 3;               // tile row 0..127
        int j = (s & 7) ^ (r & 7);    // XOR swizzle: global k-chunk in slot
        gA[i] = (by * 128 + r) * 2048 + j * 8;
        int c = bx * 128 + r;
        if (c > NCOL - 1) c = NCOL - 1;          // clamp pad columns
        int b = c / FRAMES;
        int t = c - b * FRAMES;
        gB[i] = b * PADLEN + t * HOP + j * 8;
    }

    // --- loop-invariant ds_read offsets (element units) ---
    int offA[2][4], offB[2][4];
    #pragma unroll
    for (int mt = 0; mt < 4; ++mt) {
        int row = mhalf * 64 + mt * 16 + l15;
        #pragma unroll
        for (int ks = 0; ks < 2; ++ks) {
            int j = ks * 4 + quad;
            offA[ks][mt] = row * 64 + ((j ^ (row & 7)) * 8);
        }
    }
    #pragma unroll
    for (int nt = 0; nt < 4; ++nt) {
        int rown = nhalf * 64 + nt * 16 + l15;
        #pragma unroll
        for (int ks = 0; ks < 2; ++ks) {
            int j = ks * 4 + quad;
            offB[ks][nt] = rown * 64 + ((j ^ (rown & 7)) * 8);
        }
    }

    f32x4 acc[4][4];
    const f32x4 zero = {0.f, 0.f, 0.f, 0.f};
    #pragma unroll
    for (int mt = 0; mt < 4; ++mt)
        #pragma unroll
        for (int nt = 0; nt < 4; ++nt) acc[mt][nt] = zero;

    const int ldsbase0 = wave * 64 * 8;   // wave-uniform; HW adds lane*16B

    for (int k0 = 0; k0 < 2048; k0 += 64) {
        __syncthreads();   // previous compute done before LDS overwrite
        #pragma unroll
        for (int i = 0; i < 4; ++i) {
            int lb = ldsbase0 + i * 256 * 8;
            __builtin_amdgcn_global_load_lds(
                (const __attribute__((address_space(1))) uint32_t*)(Ap + gA[i] + k0),
                (__attribute__((address_space(3))) uint32_t*)(Asm + lb),
                16, 0, 0);
            __builtin_amdgcn_global_load_lds(
                (const __attribute__((address_space(1))) uint32_t*)(xp + gB[i] + k0),
                (__attribute__((address_space(3))) uint32_t*)(Bsm + lb),
                16, 0, 0);
        }
        __syncthreads();   // compiler drains vmcnt(0) before barrier
        #pragma unroll
        for (int ks = 0; ks < 2; ++ks) {
            bf16x8 af[4], bfr[4];
            #pragma unroll
            for (int mt = 0; mt < 4; ++mt)
                af[mt] = *(const bf16x8*)(Asm + offA[ks][mt]);
            #pragma unroll
            for (int nt = 0; nt < 4; ++nt)
                bfr[nt] = *(const bf16x8*)(Bsm + offB[ks][nt]);
            #pragma unroll
            for (int mt = 0; mt < 4; ++mt)
                #pragma unroll
                for (int nt = 0; nt < 4; ++nt)
                    acc[mt][nt] = __builtin_amdgcn_mfma_f32_16x16x32_bf16(
                        af[mt], bfr[nt], acc[mt][nt], 0, 0, 0);
        }
    }

    // --- epilogue: D col = lane&15 (column c), row = quad*4+reg (freq k) ---
    // Write row k and mirror row 2048-k (k>=1), sign-flipped for bz=1.
    #pragma unroll
    for (int nt = 0; nt < 4; ++nt) {
        int c = bx * 128 + nhalf * 64 + nt * 16 + l15;
        if (c >= NCOL) continue;
        int b = c / FRAMES;
        int t = c - b * FRAMES;
        float* op = obase + (size_t)b * (N_FFT * FRAMES) + t;
        int rowbase = by * 128 + mhalf * 64 + quad * 4;
        #pragma unroll
        for (int mt = 0; mt < 4; ++mt) {
            int row = rowbase + mt * 16;
            #pragma unroll
            for (int r = 0; r < 4; ++r) {
                int k = row + r;
                float v = acc[mt][nt][r];
                op[(size_t)k * FRAMES] = v;
                if (k >= 1)
                    op[(size_t)(N_FFT - k) * FRAMES] = sg * v;
            }
        }
    }
}

// -------------------- Nyquist row (k=1024) kernel ---------------------------
// out0[b,1024,t] = dot(wc[1024,:],  xcol);  out1[b,1024,t] = dot(wsn[1024,:], xcol)
// One wave per column; lane sums 4 x bf16x8 chunks, butterfly reduce.

__global__ __launch_bounds__(256) void nyquist_row(
    const bf16* __restrict__ xp, const bf16* __restrict__ wc,
    const bf16* __restrict__ wsn, float* __restrict__ out)
{
    int c = blockIdx.x * 4 + (threadIdx.x >> 6);
    if (c >= NCOL) return;
    int lane = threadIdx.x & 63;
    int b = c / FRAMES;
    int t = c - b * FRAMES;
    const bf16* xcol = xp + (size_t)b * PADLEN + t * HOP;
    const bf16* wr   = wc  + (size_t)1024 * N_FFT;
    const bf16* wi   = wsn + (size_t)1024 * N_FFT;
    float s0 = 0.f, s1 = 0.f;
    #pragma unroll
    for (int i = 0; i < 4; ++i) {
        int off = (i * 64 + lane) * 8;
        bf16x8 xv = *(const bf16x8*)(xcol + off);
        bf16x8 wrv = *(const bf16x8*)(wr + off);
        bf16x8 wiv = *(const bf16x8*)(wi + off);
        #pragma unroll
        for (int e = 0; e < 8; ++e) {
            float xf = (float)xv[e];
            s0 += xf * (float)wrv[e];
            s1 += xf * (float)wiv[e];
        }
    }
    #pragma unroll
    for (int d = 32; d >= 1; d >>= 1) {
        s0 += __shfl_xor(s0, d, 64);
        s1 += __shfl_xor(s1, d, 64);
    }
    if (lane == 0) {
        size_t o = (size_t)b * (N_FFT * FRAMES) + (size_t)1024 * FRAMES + t;
        out[o] = s0;
        out[OHALF + o] = s1;
    }
}

// ------------------------- fallback (ws too small) -------------------------

__global__ void dft_naive(const float* __restrict__ x,
                          const float* __restrict__ wsin,
                          const float* __restrict__ wcos,
                          float* __restrict__ out)
{
    size_t i = (size_t)blockIdx.x * 256 + threadIdx.x;
    if (i >= OHALF) return;
    int t = (int)(i % FRAMES);
    size_t r = i / FRAMES;
    int k = (int)(r % N_FFT);
    int b = (int)(r / N_FFT);
    float sr = 0.f, si = 0.f;
    int base = t * HOP - N_FFT / 2;
    for (int n = 0; n < N_FFT; ++n) {
        int j = base + n;
        j = (j < 0) ? -j : ((j >= LENGTH) ? (2 * LENGTH - 2 - j) : j);
        float xv = x[(size_t)b * LENGTH + j];
        sr += xv * wcos[(size_t)k * N_FFT + n];
        si += xv * wsin[(size_t)k * N_FFT + n];
    }
    out[i] = sr;
    out[OHALF + i] = -si;
}

// ------------------------------- launch ------------------------------------

extern "C" void kernel_launch(void* const* d_in, const int* in_sizes, int n_in,
                              void* d_out, int out_size, void* d_ws, size_t ws_size,
                              hipStream_t stream) {
    const float* x    = (const float*)d_in[0];
    const float* wsin = (const float*)d_in[1];
    const float* wcos = (const float*)d_in[2];
    float* out = (float*)d_out;

    const size_t need = (size_t)(XELEMS + 2 * WELEMS) * sizeof(bf16); // ~25.2 MB
    if (ws_size < need) {
        dft_naive<<<(int)((OHALF + 255) / 256), 256, 0, stream>>>(x, wsin, wcos, out);
        return;
    }

    bf16* xp  = (bf16*)d_ws;
    bf16* wc  = xp + XELEMS;
    bf16* wsn = wc + WELEMS;

    prep_x<<<(XELEMS / 8 + 255) / 256, 256, 0, stream>>>(x, xp);
    prep_w<<<(2 * (WELEMS / 8) + 255) / 256, 256, 0, stream>>>(wcos, wsin, wc, wsn);

    dim3 grid(65, 8, 2);   // 65 n-tiles x 8 m-tiles (k=0..1023) x {cos, -sin}
    dft_gemm<<<grid, 256, 0, stream>>>(xp, wc, wsn, out);
    nyquist_row<<<(NCOL + 3) / 4, 256, 0, stream>>>(xp, wc, wsn, out);
}

// Round 3
// 272.546 us; speedup vs baseline: 1.3029x; 1.2517x over previous
//
#include <hip/hip_runtime.h>
#include <hip/hip_bf16.h>
#include <stdint.h>
#include <math.h>

// ---------------------------------------------------------------------------
// DFT_12223476924859: STFT via batched FFT (memory-bound) instead of GEMM.
//   out0[b,k,t] = Re X_t[k], out1[b,k,t] = Im X_t[k],  X_t = FFT(win * frame_t)
//   (out0 = sum w x cos, out1 = -sum w x sin == Im of forward DFT)
// Two real frames packed per complex 2048-pt FFT (Stockham radix-2, 11
// stages, LDS ping-pong, natural order). Half-spectra (k<=1024) written
// coalesced to scratch; transpose kernel produces the k-major output rows
// including conjugate mirrors (out0[2048-k]=out0[k], out1[2048-k]=-out1[k]).
// Structural floor: read 34 MB + write ~200 MB => ~35 us.
// ---------------------------------------------------------------------------

#define N_FFT   2048
#define HOP     512
#define BATCH   16
#define LENGTH  262144
#define PADLEN  (LENGTH + N_FFT)          // 264192
#define FRAMES  513
#define NCOL    (BATCH * FRAMES)          // 8208
#define OHALF   ((size_t)BATCH * N_FFT * FRAMES)  // 16,809,984
#define WELEMS  (N_FFT * N_FFT)           // 4,194,304
#define XELEMS  (BATCH * PADLEN)          // 4,227,072
#define KS      1026                      // per-frame float2 stride in scratch
#define PAIRS   257                       // ceil(513/2)

typedef __bf16 bf16;
typedef __bf16 bf16x8 __attribute__((ext_vector_type(8)));
typedef float  f32x4  __attribute__((ext_vector_type(4)));

// ============================ FFT path =====================================

__global__ void init_tables(float2* __restrict__ tw, float* __restrict__ win) {
    int i = blockIdx.x * 256 + threadIdx.x;
    if (i < 1024) {
        double a = -2.0 * M_PI * (double)i / 2048.0;
        tw[i] = make_float2((float)cos(a), (float)sin(a));
    }
    if (i < 2048) {
        double a = 2.0 * M_PI * (double)i / 2048.0;
        win[i] = (float)(0.5 - 0.5 * cos(a));
    }
}

// One block = one pair of frames (2p, 2p+1) of one batch.
// Complex packing z = wxA + i*wxB; Stockham DIF radix-2, 11 stages.
__global__ __launch_bounds__(256) void fft_pairs(
    const float* __restrict__ x, const float2* __restrict__ tw,
    const float* __restrict__ win, float2* __restrict__ sc)
{
    __shared__ float2 buf[2][2048];   // 32 KB ping-pong

    const int tid = threadIdx.x;
    const int p   = blockIdx.x;       // pair index 0..256
    const int b   = blockIdx.y;
    const int fA  = 2 * p;
    const int fB  = 2 * p + 1;
    const bool hasB = (fB < FRAMES);
    const float* xb = x + (size_t)b * LENGTH;

    // ---- load windowed frames with reflect padding ----
    #pragma unroll
    for (int j = 0; j < 8; ++j) {
        int n = tid + 256 * j;
        float w = win[n];
        int ja = fA * HOP + n - (N_FFT / 2);
        ja = (ja < 0) ? -ja : ((ja >= LENGTH) ? 2 * LENGTH - 2 - ja : ja);
        float va = xb[ja] * w;
        float vb = 0.f;
        if (hasB) {
            int jb = fB * HOP + n - (N_FFT / 2);
            jb = (jb < 0) ? -jb : ((jb >= LENGTH) ? 2 * LENGTH - 2 - jb : jb);
            vb = xb[jb] * w;
        }
        buf[0][n] = make_float2(va, vb);
    }
    __syncthreads();

    // ---- Stockham radix-2 DIF: n halves 2048->2, s doubles 1->1024 ----
    // butterfly it (0..1023): q = it & (s-1), sp = s*p = it - q
    //   in:  X[it], X[it+1024];  w = tw[sp] = e^{-2pi i p/n}
    //   out: Y[it+sp] = a+b;  Y[it+sp+s] = (a-b)*w
    int src = 0;
    for (int ls = 0; ls < 11; ++ls) {
        int s = 1 << ls;
        const float2* X = buf[src];
        float2*       Y = buf[src ^ 1];
        #pragma unroll
        for (int u = 0; u < 4; ++u) {
            int it = tid + 256 * u;
            int sp = it & ~(s - 1);
            float2 a  = X[it];
            float2 bb = X[it + 1024];
            float2 w  = tw[sp];
            float2 su = make_float2(a.x + bb.x, a.y + bb.y);
            float2 d  = make_float2(a.x - bb.x, a.y - bb.y);
            float2 dw = make_float2(d.x * w.x - d.y * w.y,
                                    d.x * w.y + d.y * w.x);
            int o = it + sp;
            Y[o]     = su;
            Y[o + s] = dw;
        }
        __syncthreads();
        src ^= 1;
    }

    // ---- unpack two real spectra, write half-spectra k=0..1024 ----
    const float2* Z = buf[src];   // src == 1 after 11 stages
    float2* scA = sc + ((size_t)b * FRAMES + fA) * KS;
    float2* scB = sc + ((size_t)b * FRAMES + fB) * KS;
    #pragma unroll
    for (int j = 0; j < 5; ++j) {
        int k = tid + 256 * j;
        if (k <= 1024) {
            float2 zk = Z[k];
            float2 zm = Z[(2048 - k) & 2047];
            // A = (Z[k] + conj(Z[N-k]))/2 ; B = -i/2 (Z[k] - conj(Z[N-k]))
            float2 A = make_float2(0.5f * (zk.x + zm.x), 0.5f * (zk.y - zm.y));
            float2 B = make_float2(0.5f * (zk.y + zm.y), 0.5f * (zm.x - zk.x));
            scA[k] = A;
            if (hasB) scB[k] = B;
        }
    }
}

// Tile transpose: sc[b][f][k] -> out[b][k][t] (+ conjugate mirror rows).
__global__ __launch_bounds__(256) void transpose_out(
    const float2* __restrict__ sc, float* __restrict__ out)
{
    __shared__ float2 tile[64][65];   // +1 pad

    const int b  = blockIdx.x;   // 16
    const int kt = blockIdx.y;   // 17 tiles of 64 covering k=0..1024
    const int ft = blockIdx.z;   // 9 chunks of 64 covering f=0..512
    const int k0 = kt * 64;
    const int f0 = ft * 64;
    const int tid = threadIdx.x;

    #pragma unroll
    for (int i = 0; i < 16; ++i) {
        int idx = tid + 256 * i;
        int fl = idx >> 6, kl = idx & 63;
        int f = f0 + fl, k = k0 + kl;
        float2 v = make_float2(0.f, 0.f);
        if (f < FRAMES && k <= 1024)
            v = sc[((size_t)b * FRAMES + f) * KS + k];
        tile[fl][kl] = v;
    }
    __syncthreads();

    const int wave = tid >> 6, lane = tid & 63;
    const int t = f0 + lane;
    const bool tok = (t < FRAMES);
    float* o0 = out + (size_t)b * ((size_t)N_FFT * FRAMES);
    float* o1 = out + OHALF + (size_t)b * ((size_t)N_FFT * FRAMES);

    for (int kl = wave; kl < 64; kl += 4) {
        int k = k0 + kl;
        if (k > 1024) continue;
        float2 v = tile[lane][kl];
        if (tok) {
            o0[(size_t)k * FRAMES + t] = v.x;
            o1[(size_t)k * FRAMES + t] = v.y;
            if (k >= 1 && k <= 1023) {
                o0[(size_t)(N_FFT - k) * FRAMES + t] = v.x;
                o1[(size_t)(N_FFT - k) * FRAMES + t] = -v.y;
            }
        }
    }
}

// ===================== fallback 1: bf16 MFMA GEMM ==========================

__global__ void prep_x(const float* __restrict__ x, bf16* __restrict__ xp) {
    int i8 = (blockIdx.x * 256 + threadIdx.x) * 8;
    if (i8 >= XELEMS) return;
    int b = i8 / PADLEN;
    int p0 = i8 - b * PADLEN;
    const float* xb = x + (size_t)b * LENGTH;
    bf16x8 v;
    #pragma unroll
    for (int e = 0; e < 8; ++e) {
        int j = p0 + e - (N_FFT / 2);
        j = (j < 0) ? -j : j;
        j = (j >= LENGTH) ? (2 * LENGTH - 2 - j) : j;
        v[e] = (bf16)xb[j];
    }
    *(bf16x8*)(xp + i8) = v;
}

__global__ void prep_w(const float* __restrict__ wcos, const float* __restrict__ wsin,
                       bf16* __restrict__ wc, bf16* __restrict__ wsn) {
    int i = blockIdx.x * 256 + threadIdx.x;
    int base = i * 8;
    if (base < WELEMS) {
        float4 a = *(const float4*)(wcos + base);
        float4 c = *(const float4*)(wcos + base + 4);
        bf16x8 v = { (bf16)a.x, (bf16)a.y, (bf16)a.z, (bf16)a.w,
                     (bf16)c.x, (bf16)c.y, (bf16)c.z, (bf16)c.w };
        *(bf16x8*)(wc + base) = v;
    } else {
        int b2 = base - WELEMS;
        if (b2 >= WELEMS) return;
        float4 a = *(const float4*)(wsin + b2);
        float4 c = *(const float4*)(wsin + b2 + 4);
        bf16x8 v = { (bf16)(-a.x), (bf16)(-a.y), (bf16)(-a.z), (bf16)(-a.w),
                     (bf16)(-c.x), (bf16)(-c.y), (bf16)(-c.z), (bf16)(-c.w) };
        *(bf16x8*)(wsn + b2) = v;
    }
}

__global__ __launch_bounds__(256) void dft_gemm(
    const bf16* __restrict__ xp, const bf16* __restrict__ wc,
    const bf16* __restrict__ wsn, float* __restrict__ out)
{
    __shared__ __align__(16) bf16 Asm[128 * 64];
    __shared__ __align__(16) bf16 Bsm[128 * 64];

    const int tid = threadIdx.x, lane = tid & 63, wave = tid >> 6;
    const int quad = lane >> 4, l15 = lane & 15;
    const int mhalf = wave >> 1, nhalf = wave & 1;
    const int bx = blockIdx.x, by = blockIdx.y, bz = blockIdx.z;

    const bf16* Ap = bz ? wsn : wc;
    float* obase = out + (size_t)bz * OHALF;
    const float sg = bz ? -1.f : 1.f;

    int gA[4], gB[4];
    #pragma unroll
    for (int i = 0; i < 4; ++i) {
        int s = i * 256 + tid;
        int r = s >> 3;
        int j = (s & 7) ^ (r & 7);
        gA[i] = (by * 128 + r) * 2048 + j * 8;
        int c = bx * 128 + r;
        if (c > NCOL - 1) c = NCOL - 1;
        int b = c / FRAMES;
        int t = c - b * FRAMES;
        gB[i] = b * PADLEN + t * HOP + j * 8;
    }
    int offA[2][4], offB[2][4];
    #pragma unroll
    for (int mt = 0; mt < 4; ++mt) {
        int row = mhalf * 64 + mt * 16 + l15;
        #pragma unroll
        for (int ks = 0; ks < 2; ++ks)
            offA[ks][mt] = row * 64 + (((ks * 4 + quad) ^ (row & 7)) * 8);
    }
    #pragma unroll
    for (int nt = 0; nt < 4; ++nt) {
        int rown = nhalf * 64 + nt * 16 + l15;
        #pragma unroll
        for (int ks = 0; ks < 2; ++ks)
            offB[ks][nt] = rown * 64 + (((ks * 4 + quad) ^ (rown & 7)) * 8);
    }

    f32x4 acc[4][4];
    const f32x4 zero = {0.f, 0.f, 0.f, 0.f};
    #pragma unroll
    for (int mt = 0; mt < 4; ++mt)
        #pragma unroll
        for (int nt = 0; nt < 4; ++nt) acc[mt][nt] = zero;

    const int ldsbase0 = wave * 64 * 8;
    for (int k0 = 0; k0 < 2048; k0 += 64) {
        __syncthreads();
        #pragma unroll
        for (int i = 0; i < 4; ++i) {
            int lb = ldsbase0 + i * 256 * 8;
            __builtin_amdgcn_global_load_lds(
                (const __attribute__((address_space(1))) uint32_t*)(Ap + gA[i] + k0),
                (__attribute__((address_space(3))) uint32_t*)(Asm + lb), 16, 0, 0);
            __builtin_amdgcn_global_load_lds(
                (const __attribute__((address_space(1))) uint32_t*)(xp + gB[i] + k0),
                (__attribute__((address_space(3))) uint32_t*)(Bsm + lb), 16, 0, 0);
        }
        __syncthreads();
        #pragma unroll
        for (int ks = 0; ks < 2; ++ks) {
            bf16x8 af[4], bfr[4];
            #pragma unroll
            for (int mt = 0; mt < 4; ++mt) af[mt] = *(const bf16x8*)(Asm + offA[ks][mt]);
            #pragma unroll
            for (int nt = 0; nt < 4; ++nt) bfr[nt] = *(const bf16x8*)(Bsm + offB[ks][nt]);
            #pragma unroll
            for (int mt = 0; mt < 4; ++mt)
                #pragma unroll
                for (int nt = 0; nt < 4; ++nt)
                    acc[mt][nt] = __builtin_amdgcn_mfma_f32_16x16x32_bf16(
                        af[mt], bfr[nt], acc[mt][nt], 0, 0, 0);
        }
    }
    #pragma unroll
    for (int nt = 0; nt < 4; ++nt) {
        int c = bx * 128 + nhalf * 64 + nt * 16 + l15;
        if (c >= NCOL) continue;
        int b = c / FRAMES;
        int t = c - b * FRAMES;
        float* op = obase + (size_t)b * (N_FFT * FRAMES) + t;
        int rowbase = by * 128 + mhalf * 64 + quad * 4;
        #pragma unroll
        for (int mt = 0; mt < 4; ++mt) {
            int row = rowbase + mt * 16;
            #pragma unroll
            for (int r = 0; r < 4; ++r) {
                int k = row + r;
                float v = acc[mt][nt][r];
                op[(size_t)k * FRAMES] = v;
                if (k >= 1) op[(size_t)(N_FFT - k) * FRAMES] = sg * v;
            }
        }
    }
}

__global__ __launch_bounds__(256) void nyquist_row(
    const bf16* __restrict__ xp, const bf16* __restrict__ wc,
    const bf16* __restrict__ wsn, float* __restrict__ out)
{
    int c = blockIdx.x * 4 + (threadIdx.x >> 6);
    if (c >= NCOL) return;
    int lane = threadIdx.x & 63;
    int b = c / FRAMES;
    int t = c - b * FRAMES;
    const bf16* xcol = xp + (size_t)b * PADLEN + t * HOP;
    const bf16* wr = wc + (size_t)1024 * N_FFT;
    const bf16* wi = wsn + (size_t)1024 * N_FFT;
    float s0 = 0.f, s1 = 0.f;
    #pragma unroll
    for (int i = 0; i < 4; ++i) {
        int off = (i * 64 + lane) * 8;
        bf16x8 xv = *(const bf16x8*)(xcol + off);
        bf16x8 wrv = *(const bf16x8*)(wr + off);
        bf16x8 wiv = *(const bf16x8*)(wi + off);
        #pragma unroll
        for (int e = 0; e < 8; ++e) {
            float xf = (float)xv[e];
            s0 += xf * (float)wrv[e];
            s1 += xf * (float)wiv[e];
        }
    }
    #pragma unroll
    for (int d = 32; d >= 1; d >>= 1) {
        s0 += __shfl_xor(s0, d, 64);
        s1 += __shfl_xor(s1, d, 64);
    }
    if (lane == 0) {
        size_t o = (size_t)b * (N_FFT * FRAMES) + (size_t)1024 * FRAMES + t;
        out[o] = s0;
        out[OHALF + o] = s1;
    }
}

// ===================== fallback 2: naive ===================================

__global__ void dft_naive(const float* __restrict__ x,
                          const float* __restrict__ wsin,
                          const float* __restrict__ wcos,
                          float* __restrict__ out)
{
    size_t i = (size_t)blockIdx.x * 256 + threadIdx.x;
    if (i >= OHALF) return;
    int t = (int)(i % FRAMES);
    size_t r = i / FRAMES;
    int k = (int)(r % N_FFT);
    int b = (int)(r / N_FFT);
    float sr = 0.f, si = 0.f;
    int base = t * HOP - N_FFT / 2;
    for (int n = 0; n < N_FFT; ++n) {
        int j = base + n;
        j = (j < 0) ? -j : ((j >= LENGTH) ? (2 * LENGTH - 2 - j) : j);
        float xv = x[(size_t)b * LENGTH + j];
        sr += xv * wcos[(size_t)k * N_FFT + n];
        si += xv * wsin[(size_t)k * N_FFT + n];
    }
    out[i] = sr;
    out[OHALF + i] = -si;
}

// ------------------------------- launch ------------------------------------

extern "C" void kernel_launch(void* const* d_in, const int* in_sizes, int n_in,
                              void* d_out, int out_size, void* d_ws, size_t ws_size,
                              hipStream_t stream) {
    const float* x    = (const float*)d_in[0];
    const float* wsin = (const float*)d_in[1];
    const float* wcos = (const float*)d_in[2];
    float* out = (float*)d_out;

    const size_t sc_f2   = (size_t)BATCH * FRAMES * KS;          // 8,421,408 float2
    const size_t need_ft = 16384 + sc_f2 * sizeof(float2);       // ~67.4 MB
    if (ws_size >= need_ft) {
        float2* tw  = (float2*)d_ws;
        float*  win = (float*)((char*)d_ws + 8192);
        float2* sc  = (float2*)((char*)d_ws + 16384);
        init_tables<<<8, 256, 0, stream>>>(tw, win);
        fft_pairs<<<dim3(PAIRS, BATCH), 256, 0, stream>>>(x, tw, win, sc);
        transpose_out<<<dim3(BATCH, 17, 9), 256, 0, stream>>>(sc, out);
        return;
    }

    const size_t need_gemm = (size_t)(XELEMS + 2 * WELEMS) * sizeof(bf16);
    if (ws_size >= need_gemm) {
        bf16* xp  = (bf16*)d_ws;
        bf16* wc  = xp + XELEMS;
        bf16* wsn = wc + WELEMS;
        prep_x<<<(XELEMS / 8 + 255) / 256, 256, 0, stream>>>(x, xp);
        prep_w<<<(2 * (WELEMS / 8) + 255) / 256, 256, 0, stream>>>(wcos, wsin, wc, wsn);
        dim3 grid(65, 8, 2);
        dft_gemm<<<grid, 256, 0, stream>>>(xp, wc, wsn, out);
        nyquist_row<<<(NCOL + 3) / 4, 256, 0, stream>>>(xp, wc, wsn, out);
        return;
    }

    dft_naive<<<(int)((OHALF + 255) / 256), 256, 0, stream>>>(x, wsin, wcos, out);
}

// Round 4
// 264.313 us; speedup vs baseline: 1.3435x; 1.0311x over previous
//
#include <hip/hip_runtime.h>
#include <stdint.h>
#include <math.h>

// ---------------------------------------------------------------------------
// DFT_12223476924859: STFT via batched real-pair FFT (memory-bound).
//   out0[b,k,t] = Re X_t[k], out1[b,k,t] = Im X_t[k],  X_t = FFT(win*frame_t)
// Two real frames packed per complex 2048-pt FFT. Stockham radix-4 DIF:
// 5 stages (s=1,4,16,64,256) + final radix-2 (twiddle=1) folded into the
// conjugate-symmetric unpack. 6 barriers total (was 12 with radix-2).
// Half-spectra k<=1024 -> scratch (coalesced); transpose kernel emits k-major
// rows incl. mirrors (out0[2048-k]=out0[k], out1[2048-k]=-out1[k]).
// Harness fills (~105us re-poison) are fixed overhead outside our control.
// ---------------------------------------------------------------------------

#define N_FFT   2048
#define HOP     512
#define BATCH   16
#define LENGTH  262144
#define FRAMES  513
#define OHALF   ((size_t)BATCH * N_FFT * FRAMES)  // 16,809,984
#define KS      1026                      // per-frame float2 stride in scratch
#define PAIRS   257                       // ceil(513/2)

__device__ __forceinline__ float2 cmul(float2 a, float2 w) {
    return make_float2(a.x * w.x - a.y * w.y, a.x * w.y + a.y * w.x);
}

// ============================ FFT path =====================================

__global__ void init_tables(float2* __restrict__ tw, float* __restrict__ win) {
    int i = blockIdx.x * 256 + threadIdx.x;   // grid covers 0..2047
    if (i < 2048) {
        double a = -2.0 * M_PI * (double)i / 2048.0;
        tw[i] = make_float2((float)cos(a), (float)sin(a));
        double aw = 2.0 * M_PI * (double)i / 2048.0;
        win[i] = (float)(0.5 - 0.5 * cos(aw));
    }
}

// One block = one pair of frames (2p, 2p+1) of one batch.
// z = wxA + i*wxB; Stockham radix-4, LDS ping-pong, natural-order output.
__global__ __launch_bounds__(256) void fft_pairs(
    const float* __restrict__ x, const float2* __restrict__ tw,
    const float* __restrict__ win, float2* __restrict__ sc)
{
    __shared__ float2 buf[2][2048];   // 32 KB ping-pong

    const int tid = threadIdx.x;
    const int p   = blockIdx.x;       // pair index 0..256
    const int b   = blockIdx.y;
    const int fA  = 2 * p;
    const int fB  = 2 * p + 1;
    const bool hasB = (fB < FRAMES);
    const float* xb = x + (size_t)b * LENGTH;

    // ---- load windowed frames with reflect padding ----
    #pragma unroll
    for (int j = 0; j < 8; ++j) {
        int n = tid + 256 * j;
        float w = win[n];
        int ja = fA * HOP + n - (N_FFT / 2);
        ja = (ja < 0) ? -ja : ((ja >= LENGTH) ? 2 * LENGTH - 2 - ja : ja);
        float va = xb[ja] * w;
        float vb = 0.f;
        if (hasB) {
            int jb = fB * HOP + n - (N_FFT / 2);
            jb = (jb < 0) ? -jb : ((jb >= LENGTH) ? 2 * LENGTH - 2 - jb : jb);
            vb = xb[jb] * w;
        }
        buf[0][n] = make_float2(va, vb);
    }
    __syncthreads();

    // ---- 5 Stockham radix-4 DIF stages: s = 1,4,16,64,256 ----
    // butterfly idx in [0,512): q = idx & (s-1), sp = idx - q (= s*p')
    //   a_m = X[idx + m*512];  Z[idx + 3*sp + m*s] = tw[m*sp] * DFT4(a)[m]
    int src = 0;
    #pragma unroll
    for (int ls = 0; ls < 5; ++ls) {
        const int s = 1 << (2 * ls);
        const float2* X = buf[src];
        float2*       Y = buf[src ^ 1];
        #pragma unroll
        for (int u = 0; u < 2; ++u) {
            int idx = tid + 256 * u;          // [0,512)
            int sp  = idx & ~(s - 1);         // s * p'
            float2 a0 = X[idx];
            float2 a1 = X[idx + 512];
            float2 a2 = X[idx + 1024];
            float2 a3 = X[idx + 1536];
            float2 t0 = make_float2(a0.x + a2.x, a0.y + a2.y);
            float2 t1 = make_float2(a0.x - a2.x, a0.y - a2.y);
            float2 t2 = make_float2(a1.x + a3.x, a1.y + a3.y);
            float2 t3 = make_float2(a1.x - a3.x, a1.y - a3.y);
            float2 y0 = make_float2(t0.x + t2.x, t0.y + t2.y);
            float2 y1 = make_float2(t1.x + t3.y, t1.y - t3.x);   // t1 - j t3
            float2 y2 = make_float2(t0.x - t2.x, t0.y - t2.y);
            float2 y3 = make_float2(t1.x - t3.y, t1.y + t3.x);   // t1 + j t3
            float2 w1 = tw[sp];
            float2 w2 = tw[2 * sp];
            float2 w3 = tw[3 * sp];
            int o = idx + 3 * sp;
            Y[o]         = y0;
            Y[o + s]     = cmul(y1, w1);
            Y[o + 2 * s] = cmul(y2, w2);
            Y[o + 3 * s] = cmul(y3, w3);
        }
        __syncthreads();
        src ^= 1;
    }

    // ---- final radix-2 stage (twiddle=1) folded into unpack ----
    // Z[m] = m<1024 ? X5[m] + X5[m+1024] : X5[m-1024] - X5[m]
    const float2* X5 = buf[src];
    float2* scA = sc + ((size_t)b * FRAMES + fA) * KS;
    float2* scB = sc + ((size_t)b * FRAMES + fB) * KS;
    #pragma unroll
    for (int j = 0; j < 5; ++j) {
        int k = tid + 256 * j;
        if (k <= 1024) {
            int m2 = (2048 - k) & 2047;
            float2 u0, u1, v0, v1;
            // zk = Z(k)
            if (k < 1024) { u0 = X5[k]; u1 = X5[k + 1024];
                            u0 = make_float2(u0.x + u1.x, u0.y + u1.y); }
            else          { u0 = X5[0]; u1 = X5[1024];
                            u0 = make_float2(u0.x - u1.x, u0.y - u1.y); }
            // zm = Z(m2)
            if (m2 < 1024) { v0 = X5[m2]; v1 = X5[m2 + 1024];
                             v0 = make_float2(v0.x + v1.x, v0.y + v1.y); }
            else           { v0 = X5[m2 - 1024]; v1 = X5[m2];
                             v0 = make_float2(v0.x - v1.x, v0.y - v1.y); }
            // A = (zk + conj(zm))/2 ; B = -i/2 (zk - conj(zm))
            float2 A = make_float2(0.5f * (u0.x + v0.x), 0.5f * (u0.y - v0.y));
            float2 B = make_float2(0.5f * (u0.y + v0.y), 0.5f * (v0.x - u0.x));
            scA[k] = A;
            if (hasB) scB[k] = B;
        }
    }
}

// Tile transpose: sc[b][f][k] -> out[b][k][t] (+ conjugate mirror rows).
__global__ __launch_bounds__(256) void transpose_out(
    const float2* __restrict__ sc, float* __restrict__ out)
{
    __shared__ float2 tile[64][65];   // +1 pad

    const int b  = blockIdx.x;   // 16
    const int kt = blockIdx.y;   // 17 tiles of 64 covering k=0..1024
    const int ft = blockIdx.z;   // 9 chunks of 64 covering f=0..512
    const int k0 = kt * 64;
    const int f0 = ft * 64;
    const int tid = threadIdx.x;

    #pragma unroll
    for (int i = 0; i < 16; ++i) {
        int idx = tid + 256 * i;
        int fl = idx >> 6, kl = idx & 63;
        int f = f0 + fl, k = k0 + kl;
        float2 v = make_float2(0.f, 0.f);
        if (f < FRAMES && k <= 1024)
            v = sc[((size_t)b * FRAMES + f) * KS + k];
        tile[fl][kl] = v;
    }
    __syncthreads();

    const int wave = tid >> 6, lane = tid & 63;
    const int t = f0 + lane;
    const bool tok = (t < FRAMES);
    float* o0 = out + (size_t)b * ((size_t)N_FFT * FRAMES);
    float* o1 = out + OHALF + (size_t)b * ((size_t)N_FFT * FRAMES);

    for (int kl = wave; kl < 64; kl += 4) {
        int k = k0 + kl;
        if (k > 1024) continue;
        float2 v = tile[lane][kl];
        if (tok) {
            o0[(size_t)k * FRAMES + t] = v.x;
            o1[(size_t)k * FRAMES + t] = v.y;
            if (k >= 1 && k <= 1023) {
                o0[(size_t)(N_FFT - k) * FRAMES + t] = v.x;
                o1[(size_t)(N_FFT - k) * FRAMES + t] = -v.y;
            }
        }
    }
}

// ===================== fallback: naive =====================================

__global__ void dft_naive(const float* __restrict__ x,
                          const float* __restrict__ wsin,
                          const float* __restrict__ wcos,
                          float* __restrict__ out)
{
    size_t i = (size_t)blockIdx.x * 256 + threadIdx.x;
    if (i >= OHALF) return;
    int t = (int)(i % FRAMES);
    size_t r = i / FRAMES;
    int k = (int)(r % N_FFT);
    int b = (int)(r / N_FFT);
    float sr = 0.f, si = 0.f;
    int base = t * HOP - N_FFT / 2;
    for (int n = 0; n < N_FFT; ++n) {
        int j = base + n;
        j = (j < 0) ? -j : ((j >= LENGTH) ? (2 * LENGTH - 2 - j) : j);
        float xv = x[(size_t)b * LENGTH + j];
        sr += xv * wcos[(size_t)k * N_FFT + n];
        si += xv * wsin[(size_t)k * N_FFT + n];
    }
    out[i] = sr;
    out[OHALF + i] = -si;
}

// ------------------------------- launch ------------------------------------

extern "C" void kernel_launch(void* const* d_in, const int* in_sizes, int n_in,
                              void* d_out, int out_size, void* d_ws, size_t ws_size,
                              hipStream_t stream) {
    const float* x    = (const float*)d_in[0];
    const float* wsin = (const float*)d_in[1];
    const float* wcos = (const float*)d_in[2];
    float* out = (float*)d_out;

    const size_t sc_f2   = (size_t)BATCH * FRAMES * KS;     // 8,421,408 float2
    const size_t need_ft = 24576 + sc_f2 * sizeof(float2);  // ~67.4 MB
    if (ws_size >= need_ft) {
        float2* tw  = (float2*)d_ws;                         // 2048 * 8 B
        float*  win = (float*)((char*)d_ws + 16384);         // 2048 * 4 B
        float2* sc  = (float2*)((char*)d_ws + 24576);
        init_tables<<<8, 256, 0, stream>>>(tw, win);
        fft_pairs<<<dim3(PAIRS, BATCH), 256, 0, stream>>>(x, tw, win, sc);
        transpose_out<<<dim3(BATCH, 17, 9), 256, 0, stream>>>(sc, out);
        return;
    }

    dft_naive<<<(int)((OHALF + 255) / 256), 256, 0, stream>>>(x, wsin, wcos, out);
}